// Round 6
// baseline (498.282 us; speedup 1.0000x reference)
//
#include <hip/hip_runtime.h>

// TargetMLPReadout, bf16x3 split-precision MFMA (gfx950), v3:
// shared A/H LDS buffer (35.8 KB -> 4 blocks/CU), 32x32 wave tiles (halved ds_read),
// GB=4 batches/block -> grid 1024 (fills 4 blocks/CU), register plan <=64 VGPR.
// out[b] = colsum relu(relu(tpart_b + A_b@W1bot) @ W2 + b2); tpart = b1 + t_b@W1top (fp32).
// x = hi+lo bf16; X@Y ~= Xhi@Yhi + Xhi@Ylo + Xlo@Yhi (absmax 0.5 proven in r4/r5).

#define DIM   128
#define NODES 64
#define NTN   63
#define GB    4

typedef short bf16x8 __attribute__((ext_vector_type(8)));
typedef float f32x4  __attribute__((ext_vector_type(4)));

static __device__ __forceinline__ unsigned short f2bf(float f) {   // RNE, no NaNs
    unsigned int u = __float_as_uint(f);
    u += 0x7FFFu + ((u >> 16) & 1u);
    return (unsigned short)(u >> 16);
}
static __device__ __forceinline__ float bf2f(unsigned short h) {
    return __uint_as_float(((unsigned int)h) << 16);
}

// wt (ushort): layer L in {0:W1bot, 1:W2} at L*32768; hi plane [n][k] 128x128, then lo. 128 KB.
__global__ void pack_wt(const float* __restrict__ W1,
                        const float* __restrict__ W2,
                        unsigned short* __restrict__ wt) {
    const int b     = blockIdx.x;        // 0..255
    const int layer = b >> 7;
    const int n     = b & 127;
    const int k     = threadIdx.x;       // 0..127
    const float* W  = layer ? W2 : (W1 + DIM * DIM);
    const float w   = W[k * DIM + n];
    const unsigned short hi = f2bf(w);
    const unsigned short lo = f2bf(w - bf2f(hi));
    unsigned short* base = wt + layer * (2 * DIM * DIM);
    base[n * DIM + k]             = hi;
    base[DIM * DIM + n * DIM + k] = lo;
}

// bf16x3 GEMM step: acc[2][2] (32x32 tile at rows r0.., cols c0..) += A(64x128 LDS) @ B.
// s = LDS base (hi plane at +0, lo plane at +16384 bytes), B planes from L2 (wt).
static __device__ __forceinline__ void gemm3(f32x4 acc[2][2],
                                             const unsigned short* s,
                                             const unsigned short* __restrict__ bhp,
                                             const unsigned short* __restrict__ blp,
                                             int r0, int c0, int l15, int g) {
    #pragma unroll
    for (int kk = 0; kk < 4; ++kk) {
        const int k0 = kk * 32 + g * 8;
        const bf16x8 bh0 = *(const bf16x8*)(bhp + (c0 + l15) * DIM + k0);
        const bf16x8 bl0 = *(const bf16x8*)(blp + (c0 + l15) * DIM + k0);
        const bf16x8 bh1 = *(const bf16x8*)(bhp + (c0 + 16 + l15) * DIM + k0);
        const bf16x8 bl1 = *(const bf16x8*)(blp + (c0 + 16 + l15) * DIM + k0);
        #pragma unroll
        for (int mi = 0; mi < 2; ++mi) {
            const int row = r0 + mi * 16 + l15;
            const int byt = row * 256 + ((k0 * 2) ^ ((row & 7) << 4));
            const bf16x8 ah = *(const bf16x8*)((const char*)s + byt);
            const bf16x8 al = *(const bf16x8*)((const char*)s + 16384 + byt);
            acc[mi][0] = __builtin_amdgcn_mfma_f32_16x16x32_bf16(ah, bh0, acc[mi][0], 0, 0, 0);
            acc[mi][1] = __builtin_amdgcn_mfma_f32_16x16x32_bf16(ah, bh1, acc[mi][1], 0, 0, 0);
            acc[mi][0] = __builtin_amdgcn_mfma_f32_16x16x32_bf16(ah, bl0, acc[mi][0], 0, 0, 0);
            acc[mi][1] = __builtin_amdgcn_mfma_f32_16x16x32_bf16(ah, bl1, acc[mi][1], 0, 0, 0);
            acc[mi][0] = __builtin_amdgcn_mfma_f32_16x16x32_bf16(al, bh0, acc[mi][0], 0, 0, 0);
            acc[mi][1] = __builtin_amdgcn_mfma_f32_16x16x32_bf16(al, bh1, acc[mi][1], 0, 0, 0);
        }
    }
}

__global__ __launch_bounds__(512, 8)
void mlp_mfma(const float* __restrict__ embs,
              const float* __restrict__ W1,
              const float* __restrict__ b1,
              const float* __restrict__ b2,
              const unsigned short* __restrict__ wt,
              float* __restrict__ out) {
    __shared__ unsigned short sAH[2][NODES * DIM];   // 32 KB shared A-then-H, hi/lo, swizzled
    __shared__ float sT[GB][DIM];                    // 2 KB tpart
    __shared__ float sR[2][DIM];                     // 1 KB cross-wave colsum

    const int tid = threadIdx.x;
    const int w   = tid >> 6;
    const int ln  = tid & 63;
    const int l15 = ln & 15;
    const int g   = ln >> 4;
    const int wc  = w & 3;              // col tile
    const int wr  = w >> 2;             // row tile
    const int c0  = wc * 32;
    const int r0  = wr * 32;
    const long bg = (long)blockIdx.x * GB;
    const float* ebase = embs + bg * (NODES * DIM);

    // ---- stage A for batch 0 (nodes 1..63, row 63 zero), hi/lo, swizzled ----
    {
        const float* e0 = ebase;
        #pragma unroll
        for (int qq = 0; qq < 4; ++qq) {
            const int Q   = tid + qq * 512;
            const int row = Q >> 5;
            const int c4  = (Q & 31) * 4;
            float4 v = make_float4(0.f, 0.f, 0.f, 0.f);
            if (row < NTN) v = *(const float4*)(e0 + (row + 1) * DIM + c4);
            const float vf[4] = {v.x, v.y, v.z, v.w};
            unsigned int hp[2], lp[2];
            #pragma unroll
            for (int e = 0; e < 2; ++e) {
                const unsigned short h0 = f2bf(vf[2 * e]),     h1 = f2bf(vf[2 * e + 1]);
                const unsigned short q0 = f2bf(vf[2 * e]     - bf2f(h0));
                const unsigned short q1 = f2bf(vf[2 * e + 1] - bf2f(h1));
                hp[e] = (unsigned int)h0 | ((unsigned int)h1 << 16);
                lp[e] = (unsigned int)q0 | ((unsigned int)q1 << 16);
            }
            const int byt = row * 256 + ((c4 * 2) ^ ((row & 7) << 4));
            *(uint2*)((char*)sAH[0] + byt) = make_uint2(hp[0], hp[1]);
            *(uint2*)((char*)sAH[1] + byt) = make_uint2(lp[0], lp[1]);
        }
    }

    // ---- tpart for GB batches: thread -> (bi, j), fp32 exact ----
    {
        const int bi = tid >> 7;             // 0..3
        const int j  = tid & 127;
        const float* t = ebase + bi * (NODES * DIM);   // node 0
        float p = b1[j];
        #pragma unroll 4
        for (int k = 0; k < DIM; ++k)
            p = fmaf(t[k], W1[k * DIM + j], p);        // W1 top half
        sT[bi][j] = p;
    }
    __syncthreads();                                   // A0 + sT ready

    for (int i = 0; i < GB; ++i) {
        // ================= layer 1: acc = tpart + A @ W1bot =================
        f32x4 acc[2][2];
        {
            const float t0 = sT[i][c0 + l15];
            const float t1 = sT[i][c0 + 16 + l15];
            #pragma unroll
            for (int mi = 0; mi < 2; ++mi) {
                acc[mi][0] = (f32x4){t0, t0, t0, t0};
                acc[mi][1] = (f32x4){t1, t1, t1, t1};
            }
        }
        gemm3(acc, sAH[0], wt, wt + DIM * DIM, r0, c0, l15, g);
        __syncthreads();                               // BAR a: A reads done

        // ---- relu -> H hi/lo over A's buffer (C: row=r0+16mi+4g+r, col=c0+16nj+l15) ----
        #pragma unroll
        for (int mi = 0; mi < 2; ++mi)
            #pragma unroll
            for (int nj = 0; nj < 2; ++nj)
                #pragma unroll
                for (int r = 0; r < 4; ++r) {
                    const int row = r0 + mi * 16 + g * 4 + r;
                    const int col = c0 + nj * 16 + l15;
                    const float v = fmaxf(acc[mi][nj][r], 0.f);
                    const unsigned short h = f2bf(v);
                    const unsigned short l = f2bf(v - bf2f(h));
                    const int byt = row * 256 + ((col * 2) ^ ((row & 7) << 4));
                    *(unsigned short*)((char*)sAH[0] + byt) = h;
                    *(unsigned short*)((char*)sAH[1] + byt) = l;
                }
        __syncthreads();                               // BAR b: H ready

        // ================= layer 2: acc = b2 + H @ W2 =================
        {
            const float t0 = b2[c0 + l15];
            const float t1 = b2[c0 + 16 + l15];
            #pragma unroll
            for (int mi = 0; mi < 2; ++mi) {
                acc[mi][0] = (f32x4){t0, t0, t0, t0};
                acc[mi][1] = (f32x4){t1, t1, t1, t1};
            }
        }
        gemm3(acc, sAH[0], wt + 2 * DIM * DIM, wt + 3 * DIM * DIM, r0, c0, l15, g);

        // ---- relu + local colsum over wave's 32 rows (skip pad row 63) ----
        float cs0 = 0.f, cs1 = 0.f;
        #pragma unroll
        for (int mi = 0; mi < 2; ++mi)
            #pragma unroll
            for (int r = 0; r < 4; ++r) {
                if (wr == 1 && mi == 1 && g == 3 && r == 3) continue;   // row 63 pad
                cs0 += fmaxf(acc[mi][0][r], 0.f);
                cs1 += fmaxf(acc[mi][1][r], 0.f);
            }
        cs0 += __shfl_xor(cs0, 16); cs0 += __shfl_xor(cs0, 32);
        cs1 += __shfl_xor(cs1, 16); cs1 += __shfl_xor(cs1, 32);
        if (g == 0) {
            sR[wr][c0 + l15]      = cs0;
            sR[wr][c0 + 16 + l15] = cs1;
        }
        __syncthreads();                               // BAR c: H reads done + sR ready

        if (wr == 0 && g == 0) {
            out[(bg + i) * DIM + c0 + l15]      = sR[0][c0 + l15]      + sR[1][c0 + l15];
            out[(bg + i) * DIM + c0 + 16 + l15] = sR[0][c0 + 16 + l15] + sR[1][c0 + 16 + l15];
        }

        // ---- stage A for batch i+1 into the shared buffer ----
        if (i + 1 < GB) {
            const float* en = ebase + (i + 1) * (NODES * DIM);
            #pragma unroll
            for (int qq = 0; qq < 4; ++qq) {
                const int Q   = tid + qq * 512;
                const int row = Q >> 5;
                const int c4  = (Q & 31) * 4;
                float4 v = make_float4(0.f, 0.f, 0.f, 0.f);
                if (row < NTN) v = *(const float4*)(en + (row + 1) * DIM + c4);
                const float vf[4] = {v.x, v.y, v.z, v.w};
                unsigned int hp[2], lp[2];
                #pragma unroll
                for (int e = 0; e < 2; ++e) {
                    const unsigned short h0 = f2bf(vf[2 * e]),     h1 = f2bf(vf[2 * e + 1]);
                    const unsigned short q0 = f2bf(vf[2 * e]     - bf2f(h0));
                    const unsigned short q1 = f2bf(vf[2 * e + 1] - bf2f(h1));
                    hp[e] = (unsigned int)h0 | ((unsigned int)h1 << 16);
                    lp[e] = (unsigned int)q0 | ((unsigned int)q1 << 16);
                }
                const int byt = row * 256 + ((c4 * 2) ^ ((row & 7) << 4));
                *(uint2*)((char*)sAH[0] + byt) = make_uint2(hp[0], hp[1]);
                *(uint2*)((char*)sAH[1] + byt) = make_uint2(lp[0], lp[1]);
            }
        }
        __syncthreads();                               // BAR d: next A ready
    }
}

extern "C" void kernel_launch(void* const* d_in, const int* in_sizes, int n_in,
                              void* d_out, int out_size, void* d_ws, size_t ws_size,
                              hipStream_t stream) {
    const float* embs = (const float*)d_in[0];
    // d_in[1] = batch_idx (int64): deterministic -> unused
    const float* W1   = (const float*)d_in[2];
    const float* b1   = (const float*)d_in[3];
    const float* W2   = (const float*)d_in[4];
    const float* b2   = (const float*)d_in[5];
    float* out        = (float*)d_out;
    unsigned short* wt = (unsigned short*)d_ws;       // 128 KB

    const int nb = in_sizes[0] / (NODES * DIM);       // 4096
    pack_wt<<<256, 128, 0, stream>>>(W1, W2, wt);
    mlp_mfma<<<nb / GB, 512, 0, stream>>>(embs, W1, b1, b2, wt, out);
}

// Round 7
// 490.779 us; speedup vs baseline: 1.0153x; 1.0153x over previous
//
#include <hip/hip_runtime.h>

// TargetMLPReadout, bf16x3 split-precision MFMA (gfx950), v4 = v3 with the spill fix:
// __launch_bounds__(512,6) instead of (512,8). r6's (512,8) forced VGPR=32 -> ~800MB
// scratch traffic (WRITE_SIZE 350MB, FETCH 557MB), MfmaUtil 5.8%. Cap 84 VGPRs keeps
// the working set (acc 16 + frags ~40) in registers; LDS 35.8KB still admits 4 blocks/CU.
// out[b] = colsum relu(relu(tpart_b + A_b@W1bot) @ W2 + b2); tpart = b1 + t_b@W1top (fp32).
// x = hi+lo bf16; X@Y ~= Xhi@Yhi + Xhi@Ylo + Xlo@Yhi (absmax 0.5 proven r4-r6).

#define DIM   128
#define NODES 64
#define NTN   63
#define GB    4

typedef short bf16x8 __attribute__((ext_vector_type(8)));
typedef float f32x4  __attribute__((ext_vector_type(4)));

static __device__ __forceinline__ unsigned short f2bf(float f) {   // RNE, no NaNs
    unsigned int u = __float_as_uint(f);
    u += 0x7FFFu + ((u >> 16) & 1u);
    return (unsigned short)(u >> 16);
}
static __device__ __forceinline__ float bf2f(unsigned short h) {
    return __uint_as_float(((unsigned int)h) << 16);
}

// wt (ushort): layer L in {0:W1bot, 1:W2} at L*32768; hi plane [n][k] 128x128, then lo. 128 KB.
__global__ void pack_wt(const float* __restrict__ W1,
                        const float* __restrict__ W2,
                        unsigned short* __restrict__ wt) {
    const int b     = blockIdx.x;        // 0..255
    const int layer = b >> 7;
    const int n     = b & 127;
    const int k     = threadIdx.x;       // 0..127
    const float* W  = layer ? W2 : (W1 + DIM * DIM);
    const float w   = W[k * DIM + n];
    const unsigned short hi = f2bf(w);
    const unsigned short lo = f2bf(w - bf2f(hi));
    unsigned short* base = wt + layer * (2 * DIM * DIM);
    base[n * DIM + k]             = hi;
    base[DIM * DIM + n * DIM + k] = lo;
}

// bf16x3 GEMM step: acc[2][2] (32x32 tile at rows r0.., cols c0..) += A(64x128 LDS) @ B.
// s = LDS base (hi plane at +0, lo plane at +16384 bytes), B planes from L2 (wt).
static __device__ __forceinline__ void gemm3(f32x4 acc[2][2],
                                             const unsigned short* s,
                                             const unsigned short* __restrict__ bhp,
                                             const unsigned short* __restrict__ blp,
                                             int r0, int c0, int l15, int g) {
    #pragma unroll
    for (int kk = 0; kk < 4; ++kk) {
        const int k0 = kk * 32 + g * 8;
        const bf16x8 bh0 = *(const bf16x8*)(bhp + (c0 + l15) * DIM + k0);
        const bf16x8 bl0 = *(const bf16x8*)(blp + (c0 + l15) * DIM + k0);
        const bf16x8 bh1 = *(const bf16x8*)(bhp + (c0 + 16 + l15) * DIM + k0);
        const bf16x8 bl1 = *(const bf16x8*)(blp + (c0 + 16 + l15) * DIM + k0);
        #pragma unroll
        for (int mi = 0; mi < 2; ++mi) {
            const int row = r0 + mi * 16 + l15;
            const int byt = row * 256 + ((k0 * 2) ^ ((row & 7) << 4));
            const bf16x8 ah = *(const bf16x8*)((const char*)s + byt);
            const bf16x8 al = *(const bf16x8*)((const char*)s + 16384 + byt);
            acc[mi][0] = __builtin_amdgcn_mfma_f32_16x16x32_bf16(ah, bh0, acc[mi][0], 0, 0, 0);
            acc[mi][1] = __builtin_amdgcn_mfma_f32_16x16x32_bf16(ah, bh1, acc[mi][1], 0, 0, 0);
            acc[mi][0] = __builtin_amdgcn_mfma_f32_16x16x32_bf16(ah, bl0, acc[mi][0], 0, 0, 0);
            acc[mi][1] = __builtin_amdgcn_mfma_f32_16x16x32_bf16(ah, bl1, acc[mi][1], 0, 0, 0);
            acc[mi][0] = __builtin_amdgcn_mfma_f32_16x16x32_bf16(al, bh0, acc[mi][0], 0, 0, 0);
            acc[mi][1] = __builtin_amdgcn_mfma_f32_16x16x32_bf16(al, bh1, acc[mi][1], 0, 0, 0);
        }
    }
}

__global__ __launch_bounds__(512, 6)
void mlp_mfma(const float* __restrict__ embs,
              const float* __restrict__ W1,
              const float* __restrict__ b1,
              const float* __restrict__ b2,
              const unsigned short* __restrict__ wt,
              float* __restrict__ out) {
    __shared__ unsigned short sAH[2][NODES * DIM];   // 32 KB shared A-then-H, hi/lo, swizzled
    __shared__ float sT[GB][DIM];                    // 2 KB tpart
    __shared__ float sR[2][DIM];                     // 1 KB cross-wave colsum

    const int tid = threadIdx.x;
    const int w   = tid >> 6;
    const int ln  = tid & 63;
    const int l15 = ln & 15;
    const int g   = ln >> 4;
    const int wc  = w & 3;              // col tile
    const int wr  = w >> 2;             // row tile
    const int c0  = wc * 32;
    const int r0  = wr * 32;
    const long bg = (long)blockIdx.x * GB;
    const float* ebase = embs + bg * (NODES * DIM);

    // ---- stage A for batch 0 (nodes 1..63, row 63 zero), hi/lo, swizzled ----
    {
        const float* e0 = ebase;
        #pragma unroll
        for (int qq = 0; qq < 4; ++qq) {
            const int Q   = tid + qq * 512;
            const int row = Q >> 5;
            const int c4  = (Q & 31) * 4;
            float4 v = make_float4(0.f, 0.f, 0.f, 0.f);
            if (row < NTN) v = *(const float4*)(e0 + (row + 1) * DIM + c4);
            const float vf[4] = {v.x, v.y, v.z, v.w};
            unsigned int hp[2], lp[2];
            #pragma unroll
            for (int e = 0; e < 2; ++e) {
                const unsigned short h0 = f2bf(vf[2 * e]),     h1 = f2bf(vf[2 * e + 1]);
                const unsigned short q0 = f2bf(vf[2 * e]     - bf2f(h0));
                const unsigned short q1 = f2bf(vf[2 * e + 1] - bf2f(h1));
                hp[e] = (unsigned int)h0 | ((unsigned int)h1 << 16);
                lp[e] = (unsigned int)q0 | ((unsigned int)q1 << 16);
            }
            const int byt = row * 256 + ((c4 * 2) ^ ((row & 7) << 4));
            *(uint2*)((char*)sAH[0] + byt) = make_uint2(hp[0], hp[1]);
            *(uint2*)((char*)sAH[1] + byt) = make_uint2(lp[0], lp[1]);
        }
    }

    // ---- tpart for GB batches: thread -> (bi, j), fp32 exact ----
    {
        const int bi = tid >> 7;             // 0..3
        const int j  = tid & 127;
        const float* t = ebase + bi * (NODES * DIM);   // node 0
        float p = b1[j];
        #pragma unroll 4
        for (int k = 0; k < DIM; ++k)
            p = fmaf(t[k], W1[k * DIM + j], p);        // W1 top half
        sT[bi][j] = p;
    }
    __syncthreads();                                   // A0 + sT ready

    for (int i = 0; i < GB; ++i) {
        // ================= layer 1: acc = tpart + A @ W1bot =================
        f32x4 acc[2][2];
        {
            const float t0 = sT[i][c0 + l15];
            const float t1 = sT[i][c0 + 16 + l15];
            #pragma unroll
            for (int mi = 0; mi < 2; ++mi) {
                acc[mi][0] = (f32x4){t0, t0, t0, t0};
                acc[mi][1] = (f32x4){t1, t1, t1, t1};
            }
        }
        gemm3(acc, sAH[0], wt, wt + DIM * DIM, r0, c0, l15, g);
        __syncthreads();                               // BAR a: A reads done

        // ---- relu -> H hi/lo over A's buffer (C: row=r0+16mi+4g+r, col=c0+16nj+l15) ----
        #pragma unroll
        for (int mi = 0; mi < 2; ++mi)
            #pragma unroll
            for (int nj = 0; nj < 2; ++nj)
                #pragma unroll
                for (int r = 0; r < 4; ++r) {
                    const int row = r0 + mi * 16 + g * 4 + r;
                    const int col = c0 + nj * 16 + l15;
                    const float v = fmaxf(acc[mi][nj][r], 0.f);
                    const unsigned short h = f2bf(v);
                    const unsigned short l = f2bf(v - bf2f(h));
                    const int byt = row * 256 + ((col * 2) ^ ((row & 7) << 4));
                    *(unsigned short*)((char*)sAH[0] + byt) = h;
                    *(unsigned short*)((char*)sAH[1] + byt) = l;
                }
        __syncthreads();                               // BAR b: H ready

        // ================= layer 2: acc = b2 + H @ W2 =================
        {
            const float t0 = b2[c0 + l15];
            const float t1 = b2[c0 + 16 + l15];
            #pragma unroll
            for (int mi = 0; mi < 2; ++mi) {
                acc[mi][0] = (f32x4){t0, t0, t0, t0};
                acc[mi][1] = (f32x4){t1, t1, t1, t1};
            }
        }
        gemm3(acc, sAH[0], wt + 2 * DIM * DIM, wt + 3 * DIM * DIM, r0, c0, l15, g);

        // ---- relu + local colsum over wave's 32 rows (skip pad row 63) ----
        float cs0 = 0.f, cs1 = 0.f;
        #pragma unroll
        for (int mi = 0; mi < 2; ++mi)
            #pragma unroll
            for (int r = 0; r < 4; ++r) {
                if (wr == 1 && mi == 1 && g == 3 && r == 3) continue;   // row 63 pad
                cs0 += fmaxf(acc[mi][0][r], 0.f);
                cs1 += fmaxf(acc[mi][1][r], 0.f);
            }
        cs0 += __shfl_xor(cs0, 16); cs0 += __shfl_xor(cs0, 32);
        cs1 += __shfl_xor(cs1, 16); cs1 += __shfl_xor(cs1, 32);
        if (g == 0) {
            sR[wr][c0 + l15]      = cs0;
            sR[wr][c0 + 16 + l15] = cs1;
        }
        __syncthreads();                               // BAR c: H reads done + sR ready

        if (wr == 0 && g == 0) {
            out[(bg + i) * DIM + c0 + l15]      = sR[0][c0 + l15]      + sR[1][c0 + l15];
            out[(bg + i) * DIM + c0 + 16 + l15] = sR[0][c0 + 16 + l15] + sR[1][c0 + 16 + l15];
        }

        // ---- stage A for batch i+1 into the shared buffer ----
        if (i + 1 < GB) {
            const float* en = ebase + (i + 1) * (NODES * DIM);
            #pragma unroll
            for (int qq = 0; qq < 4; ++qq) {
                const int Q   = tid + qq * 512;
                const int row = Q >> 5;
                const int c4  = (Q & 31) * 4;
                float4 v = make_float4(0.f, 0.f, 0.f, 0.f);
                if (row < NTN) v = *(const float4*)(en + (row + 1) * DIM + c4);
                const float vf[4] = {v.x, v.y, v.z, v.w};
                unsigned int hp[2], lp[2];
                #pragma unroll
                for (int e = 0; e < 2; ++e) {
                    const unsigned short h0 = f2bf(vf[2 * e]),     h1 = f2bf(vf[2 * e + 1]);
                    const unsigned short q0 = f2bf(vf[2 * e]     - bf2f(h0));
                    const unsigned short q1 = f2bf(vf[2 * e + 1] - bf2f(h1));
                    hp[e] = (unsigned int)h0 | ((unsigned int)h1 << 16);
                    lp[e] = (unsigned int)q0 | ((unsigned int)q1 << 16);
                }
                const int byt = row * 256 + ((c4 * 2) ^ ((row & 7) << 4));
                *(uint2*)((char*)sAH[0] + byt) = make_uint2(hp[0], hp[1]);
                *(uint2*)((char*)sAH[1] + byt) = make_uint2(lp[0], lp[1]);
            }
        }
        __syncthreads();                               // BAR d: next A ready
    }
}

extern "C" void kernel_launch(void* const* d_in, const int* in_sizes, int n_in,
                              void* d_out, int out_size, void* d_ws, size_t ws_size,
                              hipStream_t stream) {
    const float* embs = (const float*)d_in[0];
    // d_in[1] = batch_idx (int64): deterministic -> unused
    const float* W1   = (const float*)d_in[2];
    const float* b1   = (const float*)d_in[3];
    const float* W2   = (const float*)d_in[4];
    const float* b2   = (const float*)d_in[5];
    float* out        = (float*)d_out;
    unsigned short* wt = (unsigned short*)d_ws;       // 128 KB

    const int nb = in_sizes[0] / (NODES * DIM);       // 4096
    pack_wt<<<256, 128, 0, stream>>>(W1, W2, wt);
    mlp_mfma<<<nb / GB, 512, 0, stream>>>(embs, W1, b1, b2, wt, out);
}

// Round 9
// 365.302 us; speedup vs baseline: 1.3640x; 1.3435x over previous
//
#include <hip/hip_runtime.h>

// TargetMLPReadout, bf16x3 split-precision MFMA (gfx950), v5:
// 256-thread blocks (4 waves), wave tile 64 rows x 32 cols, __launch_bounds__(256,4).
// Register model (r5/r6/r7 evidence): budget = 512 TOTAL (VGPR+AGPR) per SIMD, split
// ~evenly -> at 4 waves/EU: 128 total/thread. acc 32 + ~50 transient fits; no spills.
// Each A ds_read_b128 feeds 32 cols (2 col-tiles) -> LDS reads halved vs r5.
// LDS 34.8 KB -> 4 independent blocks/CU fill barrier bubbles.
// out[b] = colsum relu(relu(tpart_b + A_b@W1bot) @ W2 + b2); tpart = b1 + t_b@W1top (fp32).
// x = hi+lo bf16; X@Y ~= Xhi@Yhi + Xhi@Ylo + Xlo@Yhi (absmax 0.5 proven r4-r7).

#define DIM   128
#define NODES 64
#define NTN   63
#define GB    4

typedef short bf16x8 __attribute__((ext_vector_type(8)));
typedef float f32x4  __attribute__((ext_vector_type(4)));

static __device__ __forceinline__ unsigned short f2bf(float f) {   // RNE, no NaNs
    unsigned int u = __float_as_uint(f);
    u += 0x7FFFu + ((u >> 16) & 1u);
    return (unsigned short)(u >> 16);
}
static __device__ __forceinline__ float bf2f(unsigned short h) {
    return __uint_as_float(((unsigned int)h) << 16);
}

// wt (ushort): layer L in {0:W1bot, 1:W2} at L*32768; hi plane [n][k] 128x128, then lo. 128 KB.
__global__ void pack_wt(const float* __restrict__ W1,
                        const float* __restrict__ W2,
                        unsigned short* __restrict__ wt) {
    const int b     = blockIdx.x;        // 0..255
    const int layer = b >> 7;
    const int n     = b & 127;
    const int k     = threadIdx.x;       // 0..127
    const float* W  = layer ? W2 : (W1 + DIM * DIM);
    const float w   = W[k * DIM + n];
    const unsigned short hi = f2bf(w);
    const unsigned short lo = f2bf(w - bf2f(hi));
    unsigned short* base = wt + layer * (2 * DIM * DIM);
    base[n * DIM + k]             = hi;
    base[DIM * DIM + n * DIM + k] = lo;
}

// bf16x3 GEMM: acc[4][2] (64 rows x 32 cols at col c0) += A(64x128 LDS hi/lo) @ B.
// s = LDS base (hi at +0, lo at +16384 BYTES). B planes stream from L2 (wt).
static __device__ __forceinline__ void gemm3(f32x4 acc[4][2],
                                             const unsigned short* s,
                                             const unsigned short* __restrict__ bhp,
                                             const unsigned short* __restrict__ blp,
                                             int c0, int l15, int g) {
    #pragma unroll
    for (int kk = 0; kk < 4; ++kk) {
        const int k0 = kk * 32 + g * 8;
        const bf16x8 bh0 = *(const bf16x8*)(bhp + (c0 + l15) * DIM + k0);
        const bf16x8 bl0 = *(const bf16x8*)(blp + (c0 + l15) * DIM + k0);
        const bf16x8 bh1 = *(const bf16x8*)(bhp + (c0 + 16 + l15) * DIM + k0);
        const bf16x8 bl1 = *(const bf16x8*)(blp + (c0 + 16 + l15) * DIM + k0);
        #pragma unroll
        for (int mi = 0; mi < 4; ++mi) {
            const int row = mi * 16 + l15;
            const int byt = row * 256 + ((k0 * 2) ^ ((row & 7) << 4));
            const bf16x8 ah = *(const bf16x8*)((const char*)s + byt);
            const bf16x8 al = *(const bf16x8*)((const char*)s + 16384 + byt);
            acc[mi][0] = __builtin_amdgcn_mfma_f32_16x16x32_bf16(ah, bh0, acc[mi][0], 0, 0, 0);
            acc[mi][1] = __builtin_amdgcn_mfma_f32_16x16x32_bf16(ah, bh1, acc[mi][1], 0, 0, 0);
            acc[mi][0] = __builtin_amdgcn_mfma_f32_16x16x32_bf16(ah, bl0, acc[mi][0], 0, 0, 0);
            acc[mi][1] = __builtin_amdgcn_mfma_f32_16x16x32_bf16(ah, bl1, acc[mi][1], 0, 0, 0);
            acc[mi][0] = __builtin_amdgcn_mfma_f32_16x16x32_bf16(al, bh0, acc[mi][0], 0, 0, 0);
            acc[mi][1] = __builtin_amdgcn_mfma_f32_16x16x32_bf16(al, bh1, acc[mi][1], 0, 0, 0);
        }
    }
}

// Stage one batch's non-target rows (nodes 1..63, row 63 zero) as hi/lo bf16, swizzled.
static __device__ __forceinline__ void stageA(unsigned short* s,
                                              const float* __restrict__ e0,
                                              int tid) {
    #pragma unroll
    for (int qq = 0; qq < 8; ++qq) {
        const int Q   = tid + qq * 256;        // 0..2047
        const int row = Q >> 5;                // 0..63
        const int c4  = (Q & 31) * 4;
        float4 v = make_float4(0.f, 0.f, 0.f, 0.f);
        if (row < NTN) v = *(const float4*)(e0 + (row + 1) * DIM + c4);
        const float vf[4] = {v.x, v.y, v.z, v.w};
        unsigned int hp[2], lp[2];
        #pragma unroll
        for (int e = 0; e < 2; ++e) {
            const unsigned short h0 = f2bf(vf[2 * e]),     h1 = f2bf(vf[2 * e + 1]);
            const unsigned short q0 = f2bf(vf[2 * e]     - bf2f(h0));
            const unsigned short q1 = f2bf(vf[2 * e + 1] - bf2f(h1));
            hp[e] = (unsigned int)h0 | ((unsigned int)h1 << 16);
            lp[e] = (unsigned int)q0 | ((unsigned int)q1 << 16);
        }
        const int byt = row * 256 + ((c4 * 2) ^ ((row & 7) << 4));
        *(uint2*)((char*)s + byt)         = make_uint2(hp[0], hp[1]);
        *(uint2*)((char*)s + 16384 + byt) = make_uint2(lp[0], lp[1]);
    }
}

__global__ __launch_bounds__(256, 4)
void mlp_mfma(const float* __restrict__ embs,
              const float* __restrict__ W1,
              const float* __restrict__ b1,
              const float* __restrict__ b2,
              const unsigned short* __restrict__ wt,
              float* __restrict__ out) {
    __shared__ unsigned short sAH[2][NODES * DIM];   // 32 KB: A then H, hi/lo, swizzled
    __shared__ float sT[GB][DIM];                    // 2 KB: tpart

    const int tid = threadIdx.x;
    const int w   = tid >> 6;            // wave 0..3 -> cols [32w, 32w+32)
    const int ln  = tid & 63;
    const int l15 = ln & 15;
    const int g   = ln >> 4;
    const int c0  = w * 32;
    const long bg = (long)blockIdx.x * GB;
    const float* ebase = embs + bg * (NODES * DIM);

    stageA(sAH[0], ebase, tid);

    // ---- tpart for GB batches: thread -> (bi, j), fp32 exact (t = node 0) ----
    #pragma unroll
    for (int q = 0; q < 2; ++q) {
        const int idx = tid + q * 256;       // 0..511
        const int bi  = idx >> 7;            // 0..3
        const int j   = idx & 127;
        const float* t = ebase + bi * (NODES * DIM);
        float p = b1[j];
        #pragma unroll 4
        for (int k = 0; k < DIM; ++k)
            p = fmaf(t[k], W1[k * DIM + j], p);        // W1 top half
        sT[bi][j] = p;
    }
    __syncthreads();                                   // A0 + sT ready

    for (int i = 0; i < GB; ++i) {
        // ================= layer 1: acc = tpart + A @ W1bot =================
        f32x4 acc[4][2];
        {
            const float t0 = sT[i][c0 + l15];
            const float t1 = sT[i][c0 + 16 + l15];
            #pragma unroll
            for (int mi = 0; mi < 4; ++mi) {
                acc[mi][0] = (f32x4){t0, t0, t0, t0};
                acc[mi][1] = (f32x4){t1, t1, t1, t1};
            }
        }
        gemm3(acc, sAH[0], wt, wt + DIM * DIM, c0, l15, g);
        __syncthreads();                               // BAR a: A reads done

        // ---- relu -> H hi/lo in place (C: row = 16mi+4g+r, col = c0+16nj+l15) ----
        #pragma unroll
        for (int mi = 0; mi < 4; ++mi)
            #pragma unroll
            for (int nj = 0; nj < 2; ++nj)
                #pragma unroll
                for (int r = 0; r < 4; ++r) {
                    const int row = mi * 16 + g * 4 + r;
                    const int col = c0 + nj * 16 + l15;
                    const float v = fmaxf(acc[mi][nj][r], 0.f);
                    const unsigned short h = f2bf(v);
                    const unsigned short l = f2bf(v - bf2f(h));
                    const int byt = row * 256 + ((col * 2) ^ ((row & 7) << 4));
                    *(unsigned short*)((char*)sAH[0] + byt)         = h;
                    *(unsigned short*)((char*)sAH[0] + 16384 + byt) = l;
                }
        __syncthreads();                               // BAR b: H ready

        // ================= layer 2: acc = b2 + H @ W2 =================
        {
            const float t0 = b2[c0 + l15];
            const float t1 = b2[c0 + 16 + l15];
            #pragma unroll
            for (int mi = 0; mi < 4; ++mi) {
                acc[mi][0] = (f32x4){t0, t0, t0, t0};
                acc[mi][1] = (f32x4){t1, t1, t1, t1};
            }
        }
        gemm3(acc, sAH[0], wt + 2 * DIM * DIM, wt + 3 * DIM * DIM, c0, l15, g);

        // ---- relu + colsum rows 0..62 (row 63 = mi3,g3,r3 pad); wave owns its cols ----
        float cs0 = 0.f, cs1 = 0.f;
        #pragma unroll
        for (int mi = 0; mi < 4; ++mi)
            #pragma unroll
            for (int r = 0; r < 4; ++r) {
                if (mi == 3 && g == 3 && r == 3) continue;   // row 63
                cs0 += fmaxf(acc[mi][0][r], 0.f);
                cs1 += fmaxf(acc[mi][1][r], 0.f);
            }
        cs0 += __shfl_xor(cs0, 16); cs0 += __shfl_xor(cs0, 32);
        cs1 += __shfl_xor(cs1, 16); cs1 += __shfl_xor(cs1, 32);
        if (g == 0) {
            out[(bg + i) * DIM + c0 + l15]      = cs0;
            out[(bg + i) * DIM + c0 + 16 + l15] = cs1;
        }
        __syncthreads();                               // BAR c: H reads done

        if (i + 1 < GB)
            stageA(sAH[0], ebase + (i + 1) * (NODES * DIM), tid);
        __syncthreads();                               // BAR d: next A ready
    }
}

extern "C" void kernel_launch(void* const* d_in, const int* in_sizes, int n_in,
                              void* d_out, int out_size, void* d_ws, size_t ws_size,
                              hipStream_t stream) {
    const float* embs = (const float*)d_in[0];
    // d_in[1] = batch_idx (int64): deterministic -> unused
    const float* W1   = (const float*)d_in[2];
    const float* b1   = (const float*)d_in[3];
    const float* W2   = (const float*)d_in[4];
    const float* b2   = (const float*)d_in[5];
    float* out        = (float*)d_out;
    unsigned short* wt = (unsigned short*)d_ws;       // 128 KB

    const int nb = in_sizes[0] / (NODES * DIM);       // 4096
    pack_wt<<<256, 128, 0, stream>>>(W1, W2, wt);
    mlp_mfma<<<nb / GB, 256, 0, stream>>>(embs, W1, b1, b2, wt, out);
}

// Round 10
// 274.776 us; speedup vs baseline: 1.8134x; 1.3295x over previous
//
#include <hip/hip_runtime.h>

// TargetMLPReadout, bf16x3 split-precision MFMA (gfx950), v6 = v5 with the real spill fix.
// Measured law (r5/r6/r7/r9): hipcc VGPR cap = 256 / launch_bounds_arg2 (arch pool 256,
// NOT the 512 unified pool). (256,4) capped at 64 -> ~300MB scratch traffic. (256,2)
// caps at 128 = exactly the HW 16-waves/CU step (m69), so actual usage ~100 VGPR keeps
// 4 blocks/CU in hardware with zero spills.
// 256-thread blocks (4 waves), wave tile 64 rows x 32 cols, GB=4 batches/block.
// out[b] = colsum relu(relu(tpart_b + A_b@W1bot) @ W2 + b2); tpart = b1 + t_b@W1top (fp32).
// x = hi+lo bf16; X@Y ~= Xhi@Yhi + Xhi@Ylo + Xlo@Yhi (absmax 0.5 proven r4-r9).

#define DIM   128
#define NODES 64
#define NTN   63
#define GB    4

typedef short bf16x8 __attribute__((ext_vector_type(8)));
typedef float f32x4  __attribute__((ext_vector_type(4)));

static __device__ __forceinline__ unsigned short f2bf(float f) {   // RNE, no NaNs
    unsigned int u = __float_as_uint(f);
    u += 0x7FFFu + ((u >> 16) & 1u);
    return (unsigned short)(u >> 16);
}
static __device__ __forceinline__ float bf2f(unsigned short h) {
    return __uint_as_float(((unsigned int)h) << 16);
}

// wt (ushort): layer L in {0:W1bot, 1:W2} at L*32768; hi plane [n][k] 128x128, then lo. 128 KB.
__global__ void pack_wt(const float* __restrict__ W1,
                        const float* __restrict__ W2,
                        unsigned short* __restrict__ wt) {
    const int b     = blockIdx.x;        // 0..255
    const int layer = b >> 7;
    const int n     = b & 127;
    const int k     = threadIdx.x;       // 0..127
    const float* W  = layer ? W2 : (W1 + DIM * DIM);
    const float w   = W[k * DIM + n];
    const unsigned short hi = f2bf(w);
    const unsigned short lo = f2bf(w - bf2f(hi));
    unsigned short* base = wt + layer * (2 * DIM * DIM);
    base[n * DIM + k]             = hi;
    base[DIM * DIM + n * DIM + k] = lo;
}

// bf16x3 GEMM: acc[4][2] (64 rows x 32 cols at col c0) += A(64x128 LDS hi/lo) @ B.
// s = LDS base (hi at +0, lo at +16384 BYTES). B planes stream from L2 (wt).
static __device__ __forceinline__ void gemm3(f32x4 acc[4][2],
                                             const unsigned short* s,
                                             const unsigned short* __restrict__ bhp,
                                             const unsigned short* __restrict__ blp,
                                             int c0, int l15, int g) {
    #pragma unroll
    for (int kk = 0; kk < 4; ++kk) {
        const int k0 = kk * 32 + g * 8;
        const bf16x8 bh0 = *(const bf16x8*)(bhp + (c0 + l15) * DIM + k0);
        const bf16x8 bl0 = *(const bf16x8*)(blp + (c0 + l15) * DIM + k0);
        const bf16x8 bh1 = *(const bf16x8*)(bhp + (c0 + 16 + l15) * DIM + k0);
        const bf16x8 bl1 = *(const bf16x8*)(blp + (c0 + 16 + l15) * DIM + k0);
        #pragma unroll
        for (int mi = 0; mi < 4; ++mi) {
            const int row = mi * 16 + l15;
            const int byt = row * 256 + ((k0 * 2) ^ ((row & 7) << 4));
            const bf16x8 ah = *(const bf16x8*)((const char*)s + byt);
            const bf16x8 al = *(const bf16x8*)((const char*)s + 16384 + byt);
            acc[mi][0] = __builtin_amdgcn_mfma_f32_16x16x32_bf16(ah, bh0, acc[mi][0], 0, 0, 0);
            acc[mi][1] = __builtin_amdgcn_mfma_f32_16x16x32_bf16(ah, bh1, acc[mi][1], 0, 0, 0);
            acc[mi][0] = __builtin_amdgcn_mfma_f32_16x16x32_bf16(ah, bl0, acc[mi][0], 0, 0, 0);
            acc[mi][1] = __builtin_amdgcn_mfma_f32_16x16x32_bf16(ah, bl1, acc[mi][1], 0, 0, 0);
            acc[mi][0] = __builtin_amdgcn_mfma_f32_16x16x32_bf16(al, bh0, acc[mi][0], 0, 0, 0);
            acc[mi][1] = __builtin_amdgcn_mfma_f32_16x16x32_bf16(al, bh1, acc[mi][1], 0, 0, 0);
        }
    }
}

// Stage one batch's non-target rows (nodes 1..63, row 63 zero) as hi/lo bf16, swizzled.
static __device__ __forceinline__ void stageA(unsigned short* s,
                                              const float* __restrict__ e0,
                                              int tid) {
    #pragma unroll
    for (int qq = 0; qq < 8; ++qq) {
        const int Q   = tid + qq * 256;        // 0..2047
        const int row = Q >> 5;                // 0..63
        const int c4  = (Q & 31) * 4;
        float4 v = make_float4(0.f, 0.f, 0.f, 0.f);
        if (row < NTN) v = *(const float4*)(e0 + (row + 1) * DIM + c4);
        const float vf[4] = {v.x, v.y, v.z, v.w};
        unsigned int hp[2], lp[2];
        #pragma unroll
        for (int e = 0; e < 2; ++e) {
            const unsigned short h0 = f2bf(vf[2 * e]),     h1 = f2bf(vf[2 * e + 1]);
            const unsigned short q0 = f2bf(vf[2 * e]     - bf2f(h0));
            const unsigned short q1 = f2bf(vf[2 * e + 1] - bf2f(h1));
            hp[e] = (unsigned int)h0 | ((unsigned int)h1 << 16);
            lp[e] = (unsigned int)q0 | ((unsigned int)q1 << 16);
        }
        const int byt = row * 256 + ((c4 * 2) ^ ((row & 7) << 4));
        *(uint2*)((char*)s + byt)         = make_uint2(hp[0], hp[1]);
        *(uint2*)((char*)s + 16384 + byt) = make_uint2(lp[0], lp[1]);
    }
}

__global__ __launch_bounds__(256, 2)
void mlp_mfma(const float* __restrict__ embs,
              const float* __restrict__ W1,
              const float* __restrict__ b1,
              const float* __restrict__ b2,
              const unsigned short* __restrict__ wt,
              float* __restrict__ out) {
    __shared__ unsigned short sAH[2][NODES * DIM];   // 32 KB: A then H, hi/lo, swizzled
    __shared__ float sT[GB][DIM];                    // 2 KB: tpart

    const int tid = threadIdx.x;
    const int w   = tid >> 6;            // wave 0..3 -> cols [32w, 32w+32)
    const int ln  = tid & 63;
    const int l15 = ln & 15;
    const int g   = ln >> 4;
    const int c0  = w * 32;
    const long bg = (long)blockIdx.x * GB;
    const float* ebase = embs + bg * (NODES * DIM);

    stageA(sAH[0], ebase, tid);

    // ---- tpart for GB batches: thread -> (bi, j), fp32 exact (t = node 0) ----
    #pragma unroll
    for (int q = 0; q < 2; ++q) {
        const int idx = tid + q * 256;       // 0..511
        const int bi  = idx >> 7;            // 0..3
        const int j   = idx & 127;
        const float* t = ebase + bi * (NODES * DIM);
        float p = b1[j];
        #pragma unroll 4
        for (int k = 0; k < DIM; ++k)
            p = fmaf(t[k], W1[k * DIM + j], p);        // W1 top half
        sT[bi][j] = p;
    }
    __syncthreads();                                   // A0 + sT ready

    for (int i = 0; i < GB; ++i) {
        // ================= layer 1: acc = tpart + A @ W1bot =================
        f32x4 acc[4][2];
        {
            const float t0 = sT[i][c0 + l15];
            const float t1 = sT[i][c0 + 16 + l15];
            #pragma unroll
            for (int mi = 0; mi < 4; ++mi) {
                acc[mi][0] = (f32x4){t0, t0, t0, t0};
                acc[mi][1] = (f32x4){t1, t1, t1, t1};
            }
        }
        gemm3(acc, sAH[0], wt, wt + DIM * DIM, c0, l15, g);
        __syncthreads();                               // BAR a: A reads done

        // ---- relu -> H hi/lo in place (C: row = 16mi+4g+r, col = c0+16nj+l15) ----
        #pragma unroll
        for (int mi = 0; mi < 4; ++mi)
            #pragma unroll
            for (int nj = 0; nj < 2; ++nj)
                #pragma unroll
                for (int r = 0; r < 4; ++r) {
                    const int row = mi * 16 + g * 4 + r;
                    const int col = c0 + nj * 16 + l15;
                    const float v = fmaxf(acc[mi][nj][r], 0.f);
                    const unsigned short h = f2bf(v);
                    const unsigned short l = f2bf(v - bf2f(h));
                    const int byt = row * 256 + ((col * 2) ^ ((row & 7) << 4));
                    *(unsigned short*)((char*)sAH[0] + byt)         = h;
                    *(unsigned short*)((char*)sAH[0] + 16384 + byt) = l;
                }
        __syncthreads();                               // BAR b: H ready

        // ================= layer 2: acc = b2 + H @ W2 =================
        {
            const float t0 = b2[c0 + l15];
            const float t1 = b2[c0 + 16 + l15];
            #pragma unroll
            for (int mi = 0; mi < 4; ++mi) {
                acc[mi][0] = (f32x4){t0, t0, t0, t0};
                acc[mi][1] = (f32x4){t1, t1, t1, t1};
            }
        }
        gemm3(acc, sAH[0], wt + 2 * DIM * DIM, wt + 3 * DIM * DIM, c0, l15, g);

        // ---- relu + colsum rows 0..62 (row 63 = mi3,g3,r3 pad); wave owns its cols ----
        float cs0 = 0.f, cs1 = 0.f;
        #pragma unroll
        for (int mi = 0; mi < 4; ++mi)
            #pragma unroll
            for (int r = 0; r < 4; ++r) {
                if (mi == 3 && g == 3 && r == 3) continue;   // row 63
                cs0 += fmaxf(acc[mi][0][r], 0.f);
                cs1 += fmaxf(acc[mi][1][r], 0.f);
            }
        cs0 += __shfl_xor(cs0, 16); cs0 += __shfl_xor(cs0, 32);
        cs1 += __shfl_xor(cs1, 16); cs1 += __shfl_xor(cs1, 32);
        if (g == 0) {
            out[(bg + i) * DIM + c0 + l15]      = cs0;
            out[(bg + i) * DIM + c0 + 16 + l15] = cs1;
        }
        __syncthreads();                               // BAR c: H reads done

        if (i + 1 < GB)
            stageA(sAH[0], ebase + (i + 1) * (NODES * DIM), tid);
        __syncthreads();                               // BAR d: next A ready
    }
}

extern "C" void kernel_launch(void* const* d_in, const int* in_sizes, int n_in,
                              void* d_out, int out_size, void* d_ws, size_t ws_size,
                              hipStream_t stream) {
    const float* embs = (const float*)d_in[0];
    // d_in[1] = batch_idx (int64): deterministic -> unused
    const float* W1   = (const float*)d_in[2];
    const float* b1   = (const float*)d_in[3];
    const float* W2   = (const float*)d_in[4];
    const float* b2   = (const float*)d_in[5];
    float* out        = (float*)d_out;
    unsigned short* wt = (unsigned short*)d_ws;       // 128 KB

    const int nb = in_sizes[0] / (NODES * DIM);       // 4096
    pack_wt<<<256, 128, 0, stream>>>(W1, W2, wt);
    mlp_mfma<<<nb / GB, 256, 0, stream>>>(embs, W1, b1, b2, wt, out);
}